// Round 15
// baseline (350.548 us; speedup 1.0000x reference)
//
#include <hip/hip_runtime.h>
#include <hip/hip_bf16.h>

typedef unsigned short u16;
typedef unsigned int u32;
typedef __bf16 bf16x8 __attribute__((ext_vector_type(8)));
typedef float f32x4 __attribute__((ext_vector_type(4)));

__device__ __forceinline__ u16 f2b(float x) {
    __hip_bfloat16 h = __float2bfloat16(x);
    return __builtin_bit_cast(u16, h);
}
__device__ __forceinline__ bf16x8 ld8(const u16* p) {
    return *reinterpret_cast<const bf16x8*>(p);
}
__device__ __forceinline__ f32x4 mfma16(bf16x8 a, bf16x8 b, f32x4 c) {
    return __builtin_amdgcn_mfma_f32_16x16x32_bf16(a, b, c, 0, 0, 0);
}

// global -> LDS direct (16B per lane). LDS dest is wave-uniform base + lane*16.
#define GLOAD16(gsrc, ldst)                                                        \
    __builtin_amdgcn_global_load_lds(                                              \
        (__attribute__((address_space(1))) void*)(uintptr_t)(gsrc),                \
        (__attribute__((address_space(3))) void*)(u32)(uintptr_t)(ldst), 16, 0, 0)

#define BARX() __builtin_amdgcn_s_barrier()
#define PRIO(p) __builtin_amdgcn_s_setprio(p)
#define VMC(N) asm volatile("s_waitcnt vmcnt(" #N ")" ::: "memory")

// ---------------------------------------------------------------- diagnostics
__global__ __launch_bounds__(256) void k_fill(float* __restrict__ out, float v, int n) {
    int i = blockIdx.x * 256 + threadIdx.x;
    if (i < n) out[i] = v;
}

// ---------------------------------------------------------------- prep kernels
__global__ __launch_bounds__(256) void k_cvt_x(const float* __restrict__ x,
                                               u16* __restrict__ xb, int n4) {
    int i = blockIdx.x * 256 + threadIdx.x;
    if (i < n4) {
        float4 v = reinterpret_cast<const float4*>(x)[i];
        ushort4 o;
        o.x = f2b(v.x); o.y = f2b(v.y); o.z = f2b(v.z); o.w = f2b(v.w);
        reinterpret_cast<ushort4*>(xb)[i] = o;
    }
}

// dst[(rowOff + n)*ldd + k] = (bf16) src[k*N + n]   (64x64 LDS-tiled transpose)
__global__ __launch_bounds__(256) void k_transp(const float* __restrict__ src, int K, int N,
                                                u16* __restrict__ dst, int rowOff, int ldd) {
    __shared__ float t[64][65];
    int n0 = blockIdx.x * 64, k0 = blockIdx.y * 64;
    int j = threadIdx.x & 63, i0 = threadIdx.x >> 6;
#pragma unroll
    for (int r = 0; r < 16; ++r) {
        int i = i0 * 16 + r;
        t[i][j] = src[(size_t)(k0 + i) * N + n0 + j];
    }
    __syncthreads();
#pragma unroll
    for (int r = 0; r < 16; ++r) {
        int i = i0 * 16 + r;
        dst[(size_t)(rowOff + n0 + i) * ldd + k0 + j] = f2b(t[j][i]);
    }
}

// ---------------------------------------------------------------- 128x128 2-phase GEMM core (r7-verified)
__device__ __forceinline__ void gemm_core128(const u16* __restrict__ A, const u16* __restrict__ B,
                                             int m0, int n0, int K,
                                             u16* lsA, u16* lsB, f32x4 (&acc)[4][4],
                                             int wid, int lane) {
    const int srow = lane >> 3;
    const int scol = ((lane & 7) * 8) ^ (srow * 8);   // pre-swizzled source col
    const int l15 = lane & 15, lg = lane >> 4;
    const int sw = (l15 & 7) * 8;                     // read-side XOR
    const int wr = wid >> 1, wc = wid & 1;
    for (int k0 = 0; k0 < K; k0 += 64) {
        __syncthreads();
#pragma unroll
        for (int i = 0; i < 4; ++i) {
            int j = i * 4 + wid;
            int row = j * 8 + srow;
            GLOAD16(A + (size_t)(m0 + row) * K + k0 + scol, lsA + j * 512);
            GLOAD16(B + (size_t)(n0 + row) * K + k0 + scol, lsB + j * 512);
        }
        __syncthreads();
#pragma unroll
        for (int kk = 0; kk < 2; ++kk) {
            bf16x8 af[4], bfv[4];
#pragma unroll
            for (int mi = 0; mi < 4; ++mi)
                af[mi] = ld8(lsA + (wr * 64 + mi * 16 + l15) * 64 + ((kk * 32 + lg * 8) ^ sw));
#pragma unroll
            for (int ni = 0; ni < 4; ++ni)
                bfv[ni] = ld8(lsB + (wc * 64 + ni * 16 + l15) * 64 + ((kk * 32 + lg * 8) ^ sw));
#pragma unroll
            for (int mi = 0; mi < 4; ++mi)
#pragma unroll
                for (int ni = 0; ni < 4; ++ni)
                    acc[mi][ni] = mfma16(af[mi], bfv[ni], acc[mi][ni]);
        }
    }
}

// ---------------------------------------------------------------- shared 8-phase helpers
__device__ __forceinline__ void stage_half(const u16* __restrict__ src, int K, int k0,
                                           u16* lsbuf, int h, int wid, int lane) {
    const int rbase = h * 128 + wid * 8 + (lane >> 3);
    const int scol = ((lane & 7) * 8) ^ ((lane >> 3) * 8);   // pre-swizzled source col
#pragma unroll
    for (int j = 0; j < 2; ++j)
        GLOAD16(src + (size_t)(rbase + j * 64) * K + k0 + scol,
                lsbuf + h * 8192 + j * 4096 + wid * 512);
}
// one 64-row x 64-col chunk (8 KB): exactly 1 global_load_lds per thread (512 thr)
__device__ __forceinline__ void stage_chunk(const u16* __restrict__ src, int K, int k0,
                                            int rowbase, u16* ldst, int wid, int lane) {
    const int row = rowbase + wid * 8 + (lane >> 3);
    const int scol = ((lane & 7) * 8) ^ ((lane >> 3) * 8);
    GLOAD16(src + (size_t)row * K + k0 + scol, ldst + wid * 512);
}

__device__ __forceinline__ void rd_a(const u16* ls, int off, int mib,
                                     int wm, int l15, int lg, int sw, bf16x8 (&aF)[4][2]) {
#pragma unroll
    for (int i = 0; i < 4; ++i)
#pragma unroll
        for (int kk = 0; kk < 2; ++kk)
            aF[i][kk] = ld8(ls + off + (wm * 128 + (mib + i) * 16 + l15) * 64 +
                            ((kk * 32 + lg * 8) ^ sw));
}
__device__ __forceinline__ void rd_b(const u16* ls, int off, int njb,
                                     int wn, int l15, int lg, int sw, bf16x8 (&bF)[2][2]) {
#pragma unroll
    for (int j = 0; j < 2; ++j)
#pragma unroll
        for (int kk = 0; kk < 2; ++kk)
            bF[j][kk] = ld8(ls + off + (wn * 64 + (njb + j) * 16 + l15) * 64 +
                            ((kk * 32 + lg * 8) ^ sw));
}
template<int MIB, int NJB>
__device__ __forceinline__ void mm8(const bf16x8 (&aF)[4][2], const bf16x8 (&bF)[2][2],
                                    f32x4 (&acc)[8][4]) {
#pragma unroll
    for (int i = 0; i < 4; ++i)
#pragma unroll
        for (int j = 0; j < 2; ++j)
#pragma unroll
            for (int kk = 0; kk < 2; ++kk)
                acc[MIB + i][NJB + j] = mfma16(aF[i][kk], bF[j][kk], acc[MIB + i][NJB + j]);
}

// ---------------------------------------------------------------- 256x256 8-phase GEMM core (r8-verified)
__device__ __forceinline__ void gemm256_core(const u16* __restrict__ A, const u16* __restrict__ B,
                                             int m0, int n0, int K,
                                             u16* lsA, u16* lsB, f32x4 (&acc)[8][4],
                                             int wid, int lane) {
    const int wm = wid >> 2, wn = wid & 3;
    const int l15 = lane & 15, lg = lane >> 4;
    const int sw = (l15 & 7) * 8;
    const u16* Arow = A + (size_t)m0 * K;
    const u16* Brow = B + (size_t)n0 * K;

    // prologue: tile0 -> buf0, tile1 -> buf1
    stage_half(Brow, K, 0, lsB, 0, wid, lane);
    stage_half(Brow, K, 0, lsB, 1, wid, lane);
    stage_half(Arow, K, 0, lsA, 0, wid, lane);
    stage_half(Arow, K, 0, lsA, 1, wid, lane);
    stage_half(Brow, K, 64, lsB + 16384, 0, wid, lane);
    stage_half(Brow, K, 64, lsB + 16384, 1, wid, lane);
    stage_half(Arow, K, 64, lsA + 16384, 0, wid, lane);
    stage_half(Arow, K, 64, lsA + 16384, 1, wid, lane);
    VMC(8);
    BARX();

    for (int k0 = 0; k0 + 128 <= K; k0 += 128) {
        const int ka2 = k0 + 128, kb2 = k0 + 192;
        const bool sa = ka2 < K, sb = kb2 < K;
        bf16x8 aF[4][2], bA[2][2], bB[2][2];

        rd_a(lsA, 0, 0, wm, l15, lg, sw, aF);
        rd_b(lsB, 0, 0, wn, l15, lg, sw, bA);
        BARX(); PRIO(1); mm8<0, 0>(aF, bA, acc); PRIO(0); BARX();
        rd_b(lsB, 0, 2, wn, l15, lg, sw, bB);
        BARX(); PRIO(1); mm8<0, 2>(aF, bB, acc); PRIO(0); BARX();
        rd_a(lsA, 0, 4, wm, l15, lg, sw, aF);
        if (sa) stage_half(Brow, K, ka2, lsB, 0, wid, lane);
        BARX(); PRIO(1); mm8<4, 2>(aF, bB, acc); PRIO(0); BARX();
        if (sa) stage_half(Brow, K, ka2, lsB, 1, wid, lane);
        if (sa) { VMC(4); } else { VMC(0); }
        BARX(); PRIO(1); mm8<4, 0>(aF, bA, acc); PRIO(0); BARX();
        rd_a(lsA, 16384, 0, wm, l15, lg, sw, aF);
        rd_b(lsB, 16384, 0, wn, l15, lg, sw, bA);
        if (sa) stage_half(Arow, K, ka2, lsA, 0, wid, lane);
        BARX(); PRIO(1); mm8<0, 0>(aF, bA, acc); PRIO(0); BARX();
        rd_b(lsB, 16384, 2, wn, l15, lg, sw, bB);
        if (sa) stage_half(Arow, K, ka2, lsA, 1, wid, lane);
        BARX(); PRIO(1); mm8<0, 2>(aF, bB, acc); PRIO(0); BARX();
        rd_a(lsA, 16384, 4, wm, l15, lg, sw, aF);
        if (sb) { stage_half(Brow, K, kb2, lsB + 16384, 0, wid, lane);
                  stage_half(Brow, K, kb2, lsB + 16384, 1, wid, lane); }
        BARX(); PRIO(1); mm8<4, 2>(aF, bB, acc); PRIO(0); BARX();
        if (sb) { stage_half(Arow, K, kb2, lsA + 16384, 0, wid, lane);
                  stage_half(Arow, K, kb2, lsA + 16384, 1, wid, lane); }
        if (sb) { VMC(8); } else { VMC(0); }
        BARX(); PRIO(1); mm8<4, 0>(aF, bA, acc); PRIO(0); BARX();
    }

    if (K % 128) {   // trailing single K-tile (even index -> buf0), fully staged+drained
        bf16x8 aF[4][2], bA[2][2], bB[2][2];
        rd_a(lsA, 0, 0, wm, l15, lg, sw, aF);
        rd_b(lsB, 0, 0, wn, l15, lg, sw, bA);
        BARX(); PRIO(1); mm8<0, 0>(aF, bA, acc); PRIO(0); BARX();
        rd_b(lsB, 0, 2, wn, l15, lg, sw, bB);
        BARX(); PRIO(1); mm8<0, 2>(aF, bB, acc); PRIO(0); BARX();
        rd_a(lsA, 0, 4, wm, l15, lg, sw, aF);
        BARX(); PRIO(1); mm8<4, 2>(aF, bB, acc); PRIO(0); BARX();
        PRIO(1); mm8<4, 0>(aF, bA, acc); PRIO(0);
    }
}

// ---------------------------------------------------------------- 256x192 6-phase GEMM core (k_gemm_out)
// v2: uniform 16-MFMA phases (was 16/8/8/16), 12 barriers/K-pair (was 16).
// Per K-tile: {mi0-3 x nj01}, {nj2 both halves}, {mi4-7 x nj01}. Stage phases (P2/P5) have
// zero ds_reads: buf's A,B fully consumed by the preceding phase's closing barrier, so
// staging 7 chunks there is race-free. Counted waits: VMC(7)@P5 (14 outstanding -> oldest
// 7 = tile t+2 landed), else VMC(0). K=4096 -> 32 iters, no tail.
__device__ __forceinline__ void rd_b2o(const u16* ls, int off, int wn, int l15, int lg, int sw,
                                       bf16x8 (&bF)[2][2]) {
#pragma unroll
    for (int j = 0; j < 2; ++j)
#pragma unroll
        for (int kk = 0; kk < 2; ++kk)
            bF[j][kk] = ld8(ls + off + (wn * 48 + j * 16 + l15) * 64 + ((kk * 32 + lg * 8) ^ sw));
}
__device__ __forceinline__ void rd_b1o(const u16* ls, int off, int wn, int l15, int lg, int sw,
                                       bf16x8 (&bF)[2]) {
#pragma unroll
    for (int kk = 0; kk < 2; ++kk)
        bF[kk] = ld8(ls + off + (wn * 48 + 32 + l15) * 64 + ((kk * 32 + lg * 8) ^ sw));
}
__device__ __forceinline__ void mmA3lo(const bf16x8 (&aF)[4][2], const bf16x8 (&bF)[2][2],
                                       f32x4 (&acc)[8][3]) {
#pragma unroll
    for (int i = 0; i < 4; ++i)
#pragma unroll
        for (int j = 0; j < 2; ++j)
#pragma unroll
            for (int kk = 0; kk < 2; ++kk)
                acc[i][j] = mfma16(aF[i][kk], bF[j][kk], acc[i][j]);
}
__device__ __forceinline__ void mmA3hi(const bf16x8 (&aF)[4][2], const bf16x8 (&bF)[2][2],
                                       f32x4 (&acc)[8][3]) {
#pragma unroll
    for (int i = 0; i < 4; ++i)
#pragma unroll
        for (int j = 0; j < 2; ++j)
#pragma unroll
            for (int kk = 0; kk < 2; ++kk)
                acc[4 + i][j] = mfma16(aF[i][kk], bF[j][kk], acc[4 + i][j]);
}
__device__ __forceinline__ void mmB3both(const bf16x8 (&aLo)[4][2], const bf16x8 (&aHi)[4][2],
                                         const bf16x8 (&bF)[2], f32x4 (&acc)[8][3]) {
#pragma unroll
    for (int i = 0; i < 4; ++i)
#pragma unroll
        for (int kk = 0; kk < 2; ++kk)
            acc[i][2] = mfma16(aLo[i][kk], bF[kk], acc[i][2]);
#pragma unroll
    for (int i = 0; i < 4; ++i)
#pragma unroll
        for (int kk = 0; kk < 2; ++kk)
            acc[4 + i][2] = mfma16(aHi[i][kk], bF[kk], acc[4 + i][2]);
}

__device__ __forceinline__ void gemm192_core(const u16* __restrict__ A, const u16* __restrict__ B,
                                             int m0, int n0, int K,
                                             u16* lsA, u16* lsB, f32x4 (&acc)[8][3],
                                             int wid, int lane) {
    const int wm = wid >> 2, wn = wid & 3;
    const int l15 = lane & 15, lg = lane >> 4;
    const int sw = (l15 & 7) * 8;
    const u16* Arow = A + (size_t)m0 * K;
    const u16* Brow = B + (size_t)n0 * K;
    // buf strides (u16): A 16384 (4 chunks), B 12288 (3 chunks)

    // prologue: tile0 (B 3 + A 4), tile1 same -> 14 issued, oldest 7 = tile0
#pragma unroll
    for (int t = 0; t < 2; ++t) {
#pragma unroll
        for (int c = 0; c < 3; ++c)
            stage_chunk(Brow, K, t * 64, c * 64, lsB + t * 12288 + c * 4096, wid, lane);
#pragma unroll
        for (int c = 0; c < 4; ++c)
            stage_chunk(Arow, K, t * 64, c * 64, lsA + t * 16384 + c * 4096, wid, lane);
    }
    VMC(7);
    BARX();

    for (int k0 = 0; k0 + 128 <= K; k0 += 128) {
        const int ka2 = k0 + 128, kb2 = k0 + 192;
        const bool sa = ka2 < K, sb = kb2 < K;
        bf16x8 aLo[4][2], aHi[4][2], bA[2][2], bB[2];

        // P0: buf0 mi0-3 x nj01  (12 ds_reads)
        rd_a(lsA, 0, 0, wm, l15, lg, sw, aLo);
        rd_b2o(lsB, 0, wn, l15, lg, sw, bA);
        BARX(); PRIO(1); mmA3lo(aLo, bA, acc); PRIO(0); BARX();
        // P1: buf0 nj2, both mi halves  (10 ds_reads)
        rd_b1o(lsB, 0, wn, l15, lg, sw, bB);
        rd_a(lsA, 0, 4, wm, l15, lg, sw, aHi);
        BARX(); PRIO(1); mmB3both(aLo, aHi, bB, acc); PRIO(0); BARX();
        // P2: stage tile t+2 -> buf0 (7 chunks; buf0 fully consumed after P1's barrier)
        if (sa) {
#pragma unroll
            for (int c = 0; c < 3; ++c)
                stage_chunk(Brow, K, ka2, c * 64, lsB + c * 4096, wid, lane);
#pragma unroll
            for (int c = 0; c < 4; ++c)
                stage_chunk(Arow, K, ka2, c * 64, lsA + c * 4096, wid, lane);
        }
        BARX(); PRIO(1); mmA3hi(aHi, bA, acc); PRIO(0); BARX();
        // P3: buf1 mi0-3 x nj01
        rd_a(lsA, 16384, 0, wm, l15, lg, sw, aLo);
        rd_b2o(lsB, 12288, wn, l15, lg, sw, bA);
        BARX(); PRIO(1); mmA3lo(aLo, bA, acc); PRIO(0); BARX();
        // P4: buf1 nj2, both mi halves
        rd_b1o(lsB, 12288, wn, l15, lg, sw, bB);
        rd_a(lsA, 16384, 4, wm, l15, lg, sw, aHi);
        BARX(); PRIO(1); mmB3both(aLo, aHi, bB, acc); PRIO(0); BARX();
        // P5: stage tile t+3 -> buf1 ; wait tile t+2 (oldest 7 of 14)
        if (sb) {
#pragma unroll
            for (int c = 0; c < 3; ++c)
                stage_chunk(Brow, K, kb2, c * 64, lsB + 12288 + c * 4096, wid, lane);
#pragma unroll
            for (int c = 0; c < 4; ++c)
                stage_chunk(Arow, K, kb2, c * 64, lsA + 16384 + c * 4096, wid, lane);
            VMC(7);
        } else { VMC(0); }
        BARX(); PRIO(1); mmA3hi(aHi, bA, acc); PRIO(0); BARX();
    }
    // K = 4096 -> no tail
}

// ---------------------------------------------------------------- GEMM1a: x @ q_w (Q only), fused bias+RoPE
__global__ __launch_bounds__(512, 2) void k_gemm_q(
        const u16* __restrict__ A, const u16* __restrict__ B,
        const float* __restrict__ qbias, const float* __restrict__ freqs,
        u16* __restrict__ Qb) {
    __shared__ __align__(16) u16 lsA[32768];
    __shared__ __align__(16) u16 lsB[32768];
    const int bid = blockIdx.x;
    const int swz = (bid & 7) * 32 + (bid >> 3);      // bijective: 256 % 8 == 0
    const int bm = swz & 15, bn = swz >> 4;
    const int m0 = bm * 256, n0 = bn * 256;
    const int wid = threadIdx.x >> 6, lane = threadIdx.x & 63;
    const int wm = wid >> 2, wn = wid & 3;
    const int l15 = lane & 15, lg = lane >> 4;
    f32x4 acc[8][4] = {};
    gemm256_core(A, B, m0, n0, 2880, lsA, lsB, acc, wid, lane);

    const int head = bn * 4 + wn;
#pragma unroll
    for (int nj = 0; nj < 2; ++nj) {
        int d = nj * 16 + l15;                 // 0..31
        float b1 = qbias[head * 64 + d];
        float b2 = qbias[head * 64 + d + 32];
#pragma unroll
        for (int mi = 0; mi < 8; ++mi) {
#pragma unroll
            for (int r = 0; r < 4; ++r) {
                int pos = m0 + wm * 128 + mi * 16 + lg * 4 + r;
                float c = freqs[pos * 64 + d];
                float s = freqs[pos * 64 + 32 + d];
                float t1 = acc[mi][nj][r] + b1;
                float t2 = acc[mi][nj + 2][r] + b2;
                size_t base = (size_t)pos * 4096 + head * 64 + d;
                Qb[base] = f2b(t1 * c - t2 * s);
                Qb[base + 32] = f2b(t2 * c + t1 * s);
            }
        }
    }
}

// ---------------------------------------------------------------- GEMM1b: x @ [k|v]w (N=1024), 128² core
__global__ __launch_bounds__(256) void k_gemm_kv(
        const u16* __restrict__ A, const u16* __restrict__ B,
        const float* __restrict__ kbias, const float* __restrict__ vbias,
        const float* __restrict__ freqs,
        u16* __restrict__ Kb, u16* __restrict__ Vt) {
    __shared__ __align__(16) u16 lsA[128 * 64];
    __shared__ __align__(16) u16 lsB[128 * 64];
    const int bid = blockIdx.x;
    const int swz = (bid & 7) * 32 + (bid >> 3);      // bijective: 256 % 8 == 0
    const int bm = swz & 31, bn = swz >> 5;           // bn 0..7
    const int m0 = bm * 128, n0 = bn * 128;
    const int wid = threadIdx.x >> 6, lane = threadIdx.x & 63;
    const int l15 = lane & 15, lg = lane >> 4;
    const int wr = wid >> 1, wc = wid & 1;
    f32x4 acc[4][4] = {};
    gemm_core128(A, B, m0, n0, 2880, lsA, lsB, acc, wid, lane);

    if (bn < 4) {   // K: bias + RoPE
        const int head = bn * 2 + wc;
#pragma unroll
        for (int ni = 0; ni < 2; ++ni) {
            int d = ni * 16 + l15;                 // 0..31
            float b1 = kbias[head * 64 + d];
            float b2 = kbias[head * 64 + d + 32];
#pragma unroll
            for (int mi = 0; mi < 4; ++mi) {
#pragma unroll
                for (int r = 0; r < 4; ++r) {
                    int pos = m0 + wr * 64 + mi * 16 + lg * 4 + r;
                    float c = freqs[pos * 64 + d];
                    float s = freqs[pos * 64 + 32 + d];
                    float t1 = acc[mi][ni][r] + b1;
                    float t2 = acc[mi][ni + 2][r] + b2;
                    size_t base = (size_t)pos * 512 + head * 64 + d;
                    Kb[base] = f2b(t1 * c - t2 * s);
                    Kb[base + 32] = f2b(t2 * c + t1 * s);
                }
            }
        }
    } else {        // V: bias only, write transposed
        const int kvh = (bn - 4) * 2 + wc;
#pragma unroll
        for (int ni = 0; ni < 4; ++ni) {
            int d = ni * 16 + l15;                 // 0..63
            float b = vbias[kvh * 64 + d];
#pragma unroll
            for (int mi = 0; mi < 4; ++mi)
#pragma unroll
                for (int r = 0; r < 4; ++r) {
                    int pos = m0 + wr * 64 + mi * 16 + lg * 4 + r;
                    Vt[(size_t)(kvh * 64 + d) * 4096 + pos] = f2b(acc[mi][ni][r] + b);
                }
        }
    }
}

// ---------------------------------------------------------------- attention v3: GQA-fused (r14-verified)
__global__ __launch_bounds__(512, 2) void k_attn(const u16* __restrict__ Qb,
                                                 const u16* __restrict__ Kb,
                                                 const u16* __restrict__ Vt,
                                                 const float* __restrict__ sinks,
                                                 u16* __restrict__ attn) {
    const float SCALE = 0.125f;
    __shared__ __align__(16) u16 Ks[256 * 64];       // 32 KB, row = key, swizzled cols
    __shared__ __align__(16) u16 Vs[64 * 256];       // 32 KB, row = d, swizzled pos-chunks
    __shared__ __align__(16) u16 P[8][16][268];      // per-wave P, 268 spreads ds_read banks
    const int nblk = blockIdx.x, kh = blockIdx.y;
    const int wid = threadIdx.x >> 6, lane = threadIdx.x & 63;
    const int l15 = lane & 15, lg = lane >> 4;
    const int sw = (l15 & 7) * 8;
    const int win0 = nblk * 128 - 128;
    const int qrow0 = nblk * 128 + wid * 16;

    // ---- stage K window: 32 segs of 8 keys x 64 d; 4 GLOAD16/thread
    {
        const int r8 = lane >> 3;
        const int scolK = ((lane & 7) * 8) ^ (r8 * 8);
#pragma unroll
        for (int i = 0; i < 4; ++i) {
            int seg = i * 8 + wid;
            int key = win0 + seg * 8 + r8;
            if (key < 0) key = 0;                              // masked later (p == 0)
            GLOAD16(Kb + (size_t)key * 512 + kh * 64 + scolK, Ks + seg * 512);
        }
    }
    // ---- stage V window: 32 segs of 2 d-rows x 256 pos; physical chunk p holds logical
    //      chunk p ^ (row&7); read at logical c uses physical c ^ (row&7).
    {
        const int r2 = lane >> 5;                              // row within seg (0..1)
        const int c32 = lane & 31;                             // physical 16B chunk
#pragma unroll
        for (int i = 0; i < 4; ++i) {
            int seg = i * 8 + wid;
            int row = seg * 2 + r2;                            // d 0..63
            int pos = win0 + ((c32 ^ (row & 7)) * 8);
            if (pos < 0) pos = 0;                              // masked later (p == 0)
            GLOAD16(Vt + (size_t)(kh * 64 + row) * 4096 + pos, Vs + seg * 512);
        }
    }
    __syncthreads();   // drains vmcnt, then barrier

    const int rq = wid * 16 + l15;                             // q row within 128
    bf16x8 qfA[2], qfB[2];
#pragma unroll
    for (int ks = 0; ks < 2; ++ks)                             // prologue: head g=0
        qfA[ks] = ld8(Qb + (size_t)(qrow0 + l15) * 4096 + (kh * 8) * 64 + ks * 32 + lg * 8);

#pragma unroll
    for (int g = 0; g < 8; ++g) {
        const int h = kh * 8 + g;
        const float sinkv = sinks[h];
        const bf16x8* qf = (g & 1) ? qfB : qfA;
        bf16x8* qn = (g & 1) ? qfA : qfB;

        // QK^T swapped: s[kt][r] = score(q = l15, key = kt*16 + lg*4 + r)
        f32x4 s[16];
#pragma unroll
        for (int kt = 0; kt < 16; ++kt) {
            f32x4 a = {};
#pragma unroll
            for (int ks = 0; ks < 2; ++ks) {
                bf16x8 kf = ld8(Ks + (kt * 16 + l15) * 64 + ((ks * 32 + lg * 8) ^ sw));
                a = mfma16(kf, qf[ks], a);
            }
            s[kt] = a;
        }
        // prefetch next head's Q during softmax
        if (g < 7) {
#pragma unroll
            for (int ks = 0; ks < 2; ++ks)
                qn[ks] = ld8(Qb + (size_t)(qrow0 + l15) * 4096 + (h + 1) * 64 + ks * 32 + lg * 8);
        }
        // mask + scale + lane-local max
        float m = -3e38f;
#pragma unroll
        for (int kt = 0; kt < 16; ++kt)
#pragma unroll
            for (int r = 0; r < 4; ++r) {
                int cc = kt * 16 + lg * 4 + r;
                bool valid = (cc > rq) && (cc <= rq + 128) && (win0 + cc >= 0);
                float v = valid ? s[kt][r] * SCALE : -1e30f;
                s[kt][r] = v;
                m = fmaxf(m, v);
            }
        m = fmaxf(m, __shfl_xor(m, 16, 64));
        m = fmaxf(m, __shfl_xor(m, 32, 64));
        m = fmaxf(m, sinkv);
        float sum = 0.f;
#pragma unroll
        for (int kt = 0; kt < 16; ++kt)
#pragma unroll
            for (int r = 0; r < 4; ++r) {
                float p = __expf(s[kt][r] - m);
                s[kt][r] = p;
                sum += p;
            }
        sum += __shfl_xor(sum, 16, 64);
        sum += __shfl_xor(sum, 32, 64);
        const float inv = 1.0f / (sum + __expf(sinkv - m));
        // normalized P -> per-wave LDS (u32-packed); no cross-wave barrier needed
#pragma unroll
        for (int kt = 0; kt < 16; ++kt) {
            u32 w0 = (u32)f2b(s[kt][0] * inv) | ((u32)f2b(s[kt][1] * inv) << 16);
            u32 w1 = (u32)f2b(s[kt][2] * inv) | ((u32)f2b(s[kt][3] * inv) << 16);
            u32* dst = (u32*)&P[wid][l15][kt * 16 + lg * 4];
            dst[0] = w0;
            dst[1] = w1;
        }

        // PV: out(16q x 64d) = P(16x256) @ V(256x64), V from LDS
        f32x4 o[4] = {};
#pragma unroll
        for (int kc = 0; kc < 8; ++kc) {
            bf16x8 pa = ld8(&P[wid][l15][kc * 32 + lg * 8]);
#pragma unroll
            for (int dc = 0; dc < 4; ++dc) {
                int row = dc * 16 + l15;
                bf16x8 vf = ld8(Vs + row * 256 + (((kc * 4 + lg) ^ (row & 7)) * 8));
                o[dc] = mfma16(pa, vf, o[dc]);
            }
        }
#pragma unroll
        for (int dc = 0; dc < 4; ++dc)
#pragma unroll
            for (int r = 0; r < 4; ++r) {
                int pos = qrow0 + lg * 4 + r;
                attn[(size_t)pos * 4096 + h * 64 + dc * 16 + l15] = f2b(o[dc][r]);
            }
    }
}

// ---------------------------------------------------------------- GEMM2: attn @ o_w + o_b -> FP32 out
__global__ __launch_bounds__(512, 2) void k_gemm_out(const u16* __restrict__ A,
                                                     const u16* __restrict__ B,
                                                     const float* __restrict__ obias,
                                                     float* __restrict__ out) {
    __shared__ __align__(16) u16 lsA[32768];   // 4 chunks x 2 buf
    __shared__ __align__(16) u16 lsB[24576];   // 3 chunks x 2 buf
    const int bid = blockIdx.x;
    const int swz = (bid & 7) * 30 + (bid >> 3);      // bijective: 240 % 8 == 0
    const int bm = swz & 15, bn = swz >> 4;           // bn 0..14
    const int m0 = bm * 256, n0 = bn * 192;
    const int wid = threadIdx.x >> 6, lane = threadIdx.x & 63;
    const int wm = wid >> 2, wn = wid & 3;
    const int l15 = lane & 15, lg = lane >> 4;
    f32x4 acc[8][3] = {};
    gemm192_core(A, B, m0, n0, 4096, lsA, lsB, acc, wid, lane);
#pragma unroll
    for (int nj = 0; nj < 3; ++nj) {
        int n = n0 + wn * 48 + nj * 16 + l15;         // < 2880 always
        float b = obias[n];
#pragma unroll
        for (int mi = 0; mi < 8; ++mi)
#pragma unroll
            for (int r = 0; r < 4; ++r) {
                int pos = m0 + wm * 128 + mi * 16 + lg * 4 + r;
                out[(size_t)pos * 2880 + n] = acc[mi][nj][r] + b;
            }
    }
}

// ---------------------------------------------------------------- launch
extern "C" void kernel_launch(void* const* d_in, const int* in_sizes, int n_in,
                              void* d_out, int out_size, void* d_ws, size_t ws_size,
                              hipStream_t stream) {
    float* outf = (float*)d_out;
    const int NOUT = 11796480;

    // environment checks -> distinctive error fills (decode via absmax)
    if (ws_size < (size_t)128581632) {
        k_fill<<<(NOUT + 255) / 256, 256, 0, stream>>>(outf, 1111.0f, NOUT);
        return;
    }
    bool sizes_ok = (n_in == 11) && (out_size == NOUT) &&
        in_sizes[0] == 11796480 && in_sizes[1] == 262144 &&
        in_sizes[2] == 11796480 && in_sizes[3] == 4096 &&
        in_sizes[4] == 1474560 && in_sizes[5] == 512 &&
        in_sizes[6] == 1474560 && in_sizes[7] == 512 &&
        in_sizes[8] == 11796480 && in_sizes[9] == 2880 && in_sizes[10] == 64;
    if (!sizes_ok) {
        k_fill<<<(NOUT + 255) / 256, 256, 0, stream>>>(outf, 2222.0f, NOUT);
        return;
    }

    const float* x  = (const float*)d_in[0];
    const float* fr = (const float*)d_in[1];
    const float* qw = (const float*)d_in[2];
    const float* qb = (const float*)d_in[3];
    const float* kw = (const float*)d_in[4];
    const float* kb = (const float*)d_in[5];
    const float* vw = (const float*)d_in[6];
    const float* vb = (const float*)d_in[7];
    const float* ow = (const float*)d_in[8];
    const float* ob = (const float*)d_in[9];
    const float* sk = (const float*)d_in[10];
    char* ws = (char*)d_ws;

    // workspace layout (bytes) — unchanged (known-good ws_size)
    u16* xb   = (u16*)(ws);                       // 4096*2880*2 = 23,592,960
    u16* WT   = (u16*)(ws + 23592960);            // 5120*2880*2 = 29,491,200 (WTo reuses this)
    u16* WTo  = WT;                               // 2880*4096*2 read-reach (fits)
    u16* Qb   = (u16*)(ws + 53084160);            // 4096*4096*2
    u16* Kb   = (u16*)(ws + 86638592);            // 4096*512*2
    u16* Vt   = (u16*)(ws + 90832896);            // 512*4096*2
    u16* attn = (u16*)(ws + 95027200);            // 4096*4096*2 ; total 128,581,632

    k_cvt_x<<<11520, 256, 0, stream>>>(x, xb, 2949120);
    // W^T for QKV: WT[n][k] = w[k][n]; n: 0..4095 Q, 4096..4607 K, 4608..5119 V
    k_transp<<<dim3(64, 45), 256, 0, stream>>>(qw, 2880, 4096, WT, 0, 2880);
    k_transp<<<dim3(8, 45), 256, 0, stream>>>(kw, 2880, 512, WT, 4096, 2880);
    k_transp<<<dim3(8, 45), 256, 0, stream>>>(vw, 2880, 512, WT, 4608, 2880);
    k_gemm_q<<<dim3(256), 512, 0, stream>>>(xb, WT, qb, fr, Qb);
    k_gemm_kv<<<dim3(256), 256, 0, stream>>>(xb, WT + (size_t)4096 * 2880, kb, vb, fr, Kb, Vt);
    k_attn<<<dim3(32, 8), 512, 0, stream>>>(Qb, Kb, Vt, sk, attn);
    // o_w^T (after GEMM1 so it can reuse WT space)
    k_transp<<<dim3(45, 64), 256, 0, stream>>>(ow, 4096, 2880, WTo, 0, 4096);
    k_gemm_out<<<dim3(240), 512, 0, stream>>>(attn, WTo, ob, outf);
}

// Round 16
// 329.469 us; speedup vs baseline: 1.0640x; 1.0640x over previous
//
#include <hip/hip_runtime.h>
#include <hip/hip_bf16.h>

typedef unsigned short u16;
typedef unsigned int u32;
typedef __bf16 bf16x8 __attribute__((ext_vector_type(8)));
typedef float f32x4 __attribute__((ext_vector_type(4)));

__device__ __forceinline__ u16 f2b(float x) {
    __hip_bfloat16 h = __float2bfloat16(x);
    return __builtin_bit_cast(u16, h);
}
__device__ __forceinline__ bf16x8 ld8(const u16* p) {
    return *reinterpret_cast<const bf16x8*>(p);
}
__device__ __forceinline__ f32x4 mfma16(bf16x8 a, bf16x8 b, f32x4 c) {
    return __builtin_amdgcn_mfma_f32_16x16x32_bf16(a, b, c, 0, 0, 0);
}

// global -> LDS direct (16B per lane). LDS dest is wave-uniform base + lane*16.
#define GLOAD16(gsrc, ldst)                                                        \
    __builtin_amdgcn_global_load_lds(                                              \
        (__attribute__((address_space(1))) void*)(uintptr_t)(gsrc),                \
        (__attribute__((address_space(3))) void*)(u32)(uintptr_t)(ldst), 16, 0, 0)

#define BARX() __builtin_amdgcn_s_barrier()
#define PRIO(p) __builtin_amdgcn_s_setprio(p)
#define VMC(N) asm volatile("s_waitcnt vmcnt(" #N ")" ::: "memory")

// ---------------------------------------------------------------- diagnostics
__global__ __launch_bounds__(256) void k_fill(float* __restrict__ out, float v, int n) {
    int i = blockIdx.x * 256 + threadIdx.x;
    if (i < n) out[i] = v;
}

// ---------------------------------------------------------------- prep kernels
__global__ __launch_bounds__(256) void k_cvt_x(const float* __restrict__ x,
                                               u16* __restrict__ xb, int n4) {
    int i = blockIdx.x * 256 + threadIdx.x;
    if (i < n4) {
        float4 v = reinterpret_cast<const float4*>(x)[i];
        ushort4 o;
        o.x = f2b(v.x); o.y = f2b(v.y); o.z = f2b(v.z); o.w = f2b(v.w);
        reinterpret_cast<ushort4*>(xb)[i] = o;
    }
}

// dst[(rowOff + n)*ldd + k] = (bf16) src[k*N + n]   (64x64 LDS-tiled transpose)
__global__ __launch_bounds__(256) void k_transp(const float* __restrict__ src, int K, int N,
                                                u16* __restrict__ dst, int rowOff, int ldd) {
    __shared__ float t[64][65];
    int n0 = blockIdx.x * 64, k0 = blockIdx.y * 64;
    int j = threadIdx.x & 63, i0 = threadIdx.x >> 6;
#pragma unroll
    for (int r = 0; r < 16; ++r) {
        int i = i0 * 16 + r;
        t[i][j] = src[(size_t)(k0 + i) * N + n0 + j];
    }
    __syncthreads();
#pragma unroll
    for (int r = 0; r < 16; ++r) {
        int i = i0 * 16 + r;
        dst[(size_t)(rowOff + n0 + i) * ldd + k0 + j] = f2b(t[j][i]);
    }
}

// ---------------------------------------------------------------- 128x128 2-phase GEMM core (r7-verified)
__device__ __forceinline__ void gemm_core128(const u16* __restrict__ A, const u16* __restrict__ B,
                                             int m0, int n0, int K,
                                             u16* lsA, u16* lsB, f32x4 (&acc)[4][4],
                                             int wid, int lane) {
    const int srow = lane >> 3;
    const int scol = ((lane & 7) * 8) ^ (srow * 8);   // pre-swizzled source col
    const int l15 = lane & 15, lg = lane >> 4;
    const int sw = (l15 & 7) * 8;                     // read-side XOR
    const int wr = wid >> 1, wc = wid & 1;
    for (int k0 = 0; k0 < K; k0 += 64) {
        __syncthreads();
#pragma unroll
        for (int i = 0; i < 4; ++i) {
            int j = i * 4 + wid;
            int row = j * 8 + srow;
            GLOAD16(A + (size_t)(m0 + row) * K + k0 + scol, lsA + j * 512);
            GLOAD16(B + (size_t)(n0 + row) * K + k0 + scol, lsB + j * 512);
        }
        __syncthreads();
#pragma unroll
        for (int kk = 0; kk < 2; ++kk) {
            bf16x8 af[4], bfv[4];
#pragma unroll
            for (int mi = 0; mi < 4; ++mi)
                af[mi] = ld8(lsA + (wr * 64 + mi * 16 + l15) * 64 + ((kk * 32 + lg * 8) ^ sw));
#pragma unroll
            for (int ni = 0; ni < 4; ++ni)
                bfv[ni] = ld8(lsB + (wc * 64 + ni * 16 + l15) * 64 + ((kk * 32 + lg * 8) ^ sw));
#pragma unroll
            for (int mi = 0; mi < 4; ++mi)
#pragma unroll
                for (int ni = 0; ni < 4; ++ni)
                    acc[mi][ni] = mfma16(af[mi], bfv[ni], acc[mi][ni]);
        }
    }
}

// ---------------------------------------------------------------- shared 8-phase helpers
__device__ __forceinline__ void stage_half(const u16* __restrict__ src, int K, int k0,
                                           u16* lsbuf, int h, int wid, int lane) {
    const int rbase = h * 128 + wid * 8 + (lane >> 3);
    const int scol = ((lane & 7) * 8) ^ ((lane >> 3) * 8);   // pre-swizzled source col
#pragma unroll
    for (int j = 0; j < 2; ++j)
        GLOAD16(src + (size_t)(rbase + j * 64) * K + k0 + scol,
                lsbuf + h * 8192 + j * 4096 + wid * 512);
}
// one 64-row x 64-col chunk (8 KB): exactly 1 global_load_lds per thread (512 thr)
__device__ __forceinline__ void stage_chunk(const u16* __restrict__ src, int K, int k0,
                                            int rowbase, u16* ldst, int wid, int lane) {
    const int row = rowbase + wid * 8 + (lane >> 3);
    const int scol = ((lane & 7) * 8) ^ ((lane >> 3) * 8);
    GLOAD16(src + (size_t)row * K + k0 + scol, ldst + wid * 512);
}

__device__ __forceinline__ void rd_a(const u16* ls, int off, int mib,
                                     int wm, int l15, int lg, int sw, bf16x8 (&aF)[4][2]) {
#pragma unroll
    for (int i = 0; i < 4; ++i)
#pragma unroll
        for (int kk = 0; kk < 2; ++kk)
            aF[i][kk] = ld8(ls + off + (wm * 128 + (mib + i) * 16 + l15) * 64 +
                            ((kk * 32 + lg * 8) ^ sw));
}
__device__ __forceinline__ void rd_b(const u16* ls, int off, int njb,
                                     int wn, int l15, int lg, int sw, bf16x8 (&bF)[2][2]) {
#pragma unroll
    for (int j = 0; j < 2; ++j)
#pragma unroll
        for (int kk = 0; kk < 2; ++kk)
            bF[j][kk] = ld8(ls + off + (wn * 64 + (njb + j) * 16 + l15) * 64 +
                            ((kk * 32 + lg * 8) ^ sw));
}
template<int MIB, int NJB>
__device__ __forceinline__ void mm8(const bf16x8 (&aF)[4][2], const bf16x8 (&bF)[2][2],
                                    f32x4 (&acc)[8][4]) {
#pragma unroll
    for (int i = 0; i < 4; ++i)
#pragma unroll
        for (int j = 0; j < 2; ++j)
#pragma unroll
            for (int kk = 0; kk < 2; ++kk)
                acc[MIB + i][NJB + j] = mfma16(aF[i][kk], bF[j][kk], acc[MIB + i][NJB + j]);
}

// ---------------------------------------------------------------- 256x256 8-phase GEMM core (r8-verified)
__device__ __forceinline__ void gemm256_core(const u16* __restrict__ A, const u16* __restrict__ B,
                                             int m0, int n0, int K,
                                             u16* lsA, u16* lsB, f32x4 (&acc)[8][4],
                                             int wid, int lane) {
    const int wm = wid >> 2, wn = wid & 3;
    const int l15 = lane & 15, lg = lane >> 4;
    const int sw = (l15 & 7) * 8;
    const u16* Arow = A + (size_t)m0 * K;
    const u16* Brow = B + (size_t)n0 * K;

    // prologue: tile0 -> buf0, tile1 -> buf1
    stage_half(Brow, K, 0, lsB, 0, wid, lane);
    stage_half(Brow, K, 0, lsB, 1, wid, lane);
    stage_half(Arow, K, 0, lsA, 0, wid, lane);
    stage_half(Arow, K, 0, lsA, 1, wid, lane);
    stage_half(Brow, K, 64, lsB + 16384, 0, wid, lane);
    stage_half(Brow, K, 64, lsB + 16384, 1, wid, lane);
    stage_half(Arow, K, 64, lsA + 16384, 0, wid, lane);
    stage_half(Arow, K, 64, lsA + 16384, 1, wid, lane);
    VMC(8);
    BARX();

    for (int k0 = 0; k0 + 128 <= K; k0 += 128) {
        const int ka2 = k0 + 128, kb2 = k0 + 192;
        const bool sa = ka2 < K, sb = kb2 < K;
        bf16x8 aF[4][2], bA[2][2], bB[2][2];

        rd_a(lsA, 0, 0, wm, l15, lg, sw, aF);
        rd_b(lsB, 0, 0, wn, l15, lg, sw, bA);
        BARX(); PRIO(1); mm8<0, 0>(aF, bA, acc); PRIO(0); BARX();
        rd_b(lsB, 0, 2, wn, l15, lg, sw, bB);
        BARX(); PRIO(1); mm8<0, 2>(aF, bB, acc); PRIO(0); BARX();
        rd_a(lsA, 0, 4, wm, l15, lg, sw, aF);
        if (sa) stage_half(Brow, K, ka2, lsB, 0, wid, lane);
        BARX(); PRIO(1); mm8<4, 2>(aF, bB, acc); PRIO(0); BARX();
        if (sa) stage_half(Brow, K, ka2, lsB, 1, wid, lane);
        if (sa) { VMC(4); } else { VMC(0); }
        BARX(); PRIO(1); mm8<4, 0>(aF, bA, acc); PRIO(0); BARX();
        rd_a(lsA, 16384, 0, wm, l15, lg, sw, aF);
        rd_b(lsB, 16384, 0, wn, l15, lg, sw, bA);
        if (sa) stage_half(Arow, K, ka2, lsA, 0, wid, lane);
        BARX(); PRIO(1); mm8<0, 0>(aF, bA, acc); PRIO(0); BARX();
        rd_b(lsB, 16384, 2, wn, l15, lg, sw, bB);
        if (sa) stage_half(Arow, K, ka2, lsA, 1, wid, lane);
        BARX(); PRIO(1); mm8<0, 2>(aF, bB, acc); PRIO(0); BARX();
        rd_a(lsA, 16384, 4, wm, l15, lg, sw, aF);
        if (sb) { stage_half(Brow, K, kb2, lsB + 16384, 0, wid, lane);
                  stage_half(Brow, K, kb2, lsB + 16384, 1, wid, lane); }
        BARX(); PRIO(1); mm8<4, 2>(aF, bB, acc); PRIO(0); BARX();
        if (sb) { stage_half(Arow, K, kb2, lsA + 16384, 0, wid, lane);
                  stage_half(Arow, K, kb2, lsA + 16384, 1, wid, lane); }
        if (sb) { VMC(8); } else { VMC(0); }
        BARX(); PRIO(1); mm8<4, 0>(aF, bA, acc); PRIO(0); BARX();
    }

    if (K % 128) {   // trailing single K-tile (even index -> buf0), fully staged+drained
        bf16x8 aF[4][2], bA[2][2], bB[2][2];
        rd_a(lsA, 0, 0, wm, l15, lg, sw, aF);
        rd_b(lsB, 0, 0, wn, l15, lg, sw, bA);
        BARX(); PRIO(1); mm8<0, 0>(aF, bA, acc); PRIO(0); BARX();
        rd_b(lsB, 0, 2, wn, l15, lg, sw, bB);
        BARX(); PRIO(1); mm8<0, 2>(aF, bB, acc); PRIO(0); BARX();
        rd_a(lsA, 0, 4, wm, l15, lg, sw, aF);
        BARX(); PRIO(1); mm8<4, 2>(aF, bB, acc); PRIO(0); BARX();
        PRIO(1); mm8<4, 0>(aF, bA, acc); PRIO(0);
    }
}

// ---------------------------------------------------------------- 256x192 8-phase GEMM core (r12-verified; r15's 6-phase reverted)
__device__ __forceinline__ void rd_b2o(const u16* ls, int off, int wn, int l15, int lg, int sw,
                                       bf16x8 (&bF)[2][2]) {
#pragma unroll
    for (int j = 0; j < 2; ++j)
#pragma unroll
        for (int kk = 0; kk < 2; ++kk)
            bF[j][kk] = ld8(ls + off + (wn * 48 + j * 16 + l15) * 64 + ((kk * 32 + lg * 8) ^ sw));
}
__device__ __forceinline__ void rd_b1o(const u16* ls, int off, int wn, int l15, int lg, int sw,
                                       bf16x8 (&bF)[2]) {
#pragma unroll
    for (int kk = 0; kk < 2; ++kk)
        bF[kk] = ld8(ls + off + (wn * 48 + 32 + l15) * 64 + ((kk * 32 + lg * 8) ^ sw));
}
template<int MIB>
__device__ __forceinline__ void mmA3(const bf16x8 (&aF)[4][2], const bf16x8 (&bF)[2][2],
                                     f32x4 (&acc)[8][3]) {
#pragma unroll
    for (int i = 0; i < 4; ++i)
#pragma unroll
        for (int j = 0; j < 2; ++j)
#pragma unroll
            for (int kk = 0; kk < 2; ++kk)
                acc[MIB + i][j] = mfma16(aF[i][kk], bF[j][kk], acc[MIB + i][j]);
}
template<int MIB>
__device__ __forceinline__ void mmB3(const bf16x8 (&aF)[4][2], const bf16x8 (&bF)[2],
                                     f32x4 (&acc)[8][3]) {
#pragma unroll
    for (int i = 0; i < 4; ++i)
#pragma unroll
        for (int kk = 0; kk < 2; ++kk)
            acc[MIB + i][2] = mfma16(aF[i][kk], bF[kk], acc[MIB + i][2]);
}

__device__ __forceinline__ void gemm192_core(const u16* __restrict__ A, const u16* __restrict__ B,
                                             int m0, int n0, int K,
                                             u16* lsA, u16* lsB, f32x4 (&acc)[8][3],
                                             int wid, int lane) {
    const int wm = wid >> 2, wn = wid & 3;
    const int l15 = lane & 15, lg = lane >> 4;
    const int sw = (l15 & 7) * 8;
    const u16* Arow = A + (size_t)m0 * K;
    const u16* Brow = B + (size_t)n0 * K;

    // prologue: tile0 (B 3 + A 4), tile1 same -> 14 issued, oldest 7 = tile0
#pragma unroll
    for (int t = 0; t < 2; ++t) {
#pragma unroll
        for (int c = 0; c < 3; ++c)
            stage_chunk(Brow, K, t * 64, c * 64, lsB + t * 12288 + c * 4096, wid, lane);
#pragma unroll
        for (int c = 0; c < 4; ++c)
            stage_chunk(Arow, K, t * 64, c * 64, lsA + t * 16384 + c * 4096, wid, lane);
    }
    VMC(7);
    BARX();

    for (int k0 = 0; k0 + 128 <= K; k0 += 128) {
        const int ka2 = k0 + 128, kb2 = k0 + 192;
        const bool sa = ka2 < K, sb = kb2 < K;
        bf16x8 aF[4][2], bA[2][2], bB[2];

        rd_a(lsA, 0, 0, wm, l15, lg, sw, aF);
        rd_b2o(lsB, 0, wn, l15, lg, sw, bA);
        BARX(); PRIO(1); mmA3<0>(aF, bA, acc); PRIO(0); BARX();
        rd_b1o(lsB, 0, wn, l15, lg, sw, bB);
        BARX(); PRIO(1); mmB3<0>(aF, bB, acc); PRIO(0); BARX();
        rd_a(lsA, 0, 4, wm, l15, lg, sw, aF);
        if (sa) {
#pragma unroll
            for (int c = 0; c < 3; ++c)
                stage_chunk(Brow, K, ka2, c * 64, lsB + c * 4096, wid, lane);
        }
        BARX(); PRIO(1); mmB3<4>(aF, bB, acc); PRIO(0); BARX();
        if (sa) {
#pragma unroll
            for (int c = 0; c < 2; ++c)
                stage_chunk(Arow, K, ka2, c * 64, lsA + c * 4096, wid, lane);
            VMC(5);
        } else { VMC(0); }
        BARX(); PRIO(1); mmA3<4>(aF, bA, acc); PRIO(0); BARX();
        rd_a(lsA, 16384, 0, wm, l15, lg, sw, aF);
        rd_b2o(lsB, 12288, wn, l15, lg, sw, bA);
        if (sa) {
#pragma unroll
            for (int c = 2; c < 4; ++c)
                stage_chunk(Arow, K, ka2, c * 64, lsA + c * 4096, wid, lane);
        }
        BARX(); PRIO(1); mmA3<0>(aF, bA, acc); PRIO(0); BARX();
        rd_b1o(lsB, 12288, wn, l15, lg, sw, bB);
        BARX(); PRIO(1); mmB3<0>(aF, bB, acc); PRIO(0); BARX();
        rd_a(lsA, 16384, 4, wm, l15, lg, sw, aF);
        if (sb) {
#pragma unroll
            for (int c = 0; c < 3; ++c)
                stage_chunk(Brow, K, kb2, c * 64, lsB + 12288 + c * 4096, wid, lane);
        }
        BARX(); PRIO(1); mmB3<4>(aF, bB, acc); PRIO(0); BARX();
        if (sb) {
#pragma unroll
            for (int c = 0; c < 4; ++c)
                stage_chunk(Arow, K, kb2, c * 64, lsA + 16384 + c * 4096, wid, lane);
            VMC(7);
        } else { VMC(0); }
        BARX(); PRIO(1); mmA3<4>(aF, bA, acc); PRIO(0); BARX();
    }
    // K = 4096 -> no tail
}

// ---------------------------------------------------------------- GEMM1a: x @ q_w (Q only), fused bias+RoPE
__global__ __launch_bounds__(512, 2) void k_gemm_q(
        const u16* __restrict__ A, const u16* __restrict__ B,
        const float* __restrict__ qbias, const float* __restrict__ freqs,
        u16* __restrict__ Qb) {
    __shared__ __align__(16) u16 lsA[32768];
    __shared__ __align__(16) u16 lsB[32768];
    const int bid = blockIdx.x;
    const int swz = (bid & 7) * 32 + (bid >> 3);      // bijective: 256 % 8 == 0
    const int bm = swz & 15, bn = swz >> 4;
    const int m0 = bm * 256, n0 = bn * 256;
    const int wid = threadIdx.x >> 6, lane = threadIdx.x & 63;
    const int wm = wid >> 2, wn = wid & 3;
    const int l15 = lane & 15, lg = lane >> 4;
    f32x4 acc[8][4] = {};
    gemm256_core(A, B, m0, n0, 2880, lsA, lsB, acc, wid, lane);

    const int head = bn * 4 + wn;
#pragma unroll
    for (int nj = 0; nj < 2; ++nj) {
        int d = nj * 16 + l15;                 // 0..31
        float b1 = qbias[head * 64 + d];
        float b2 = qbias[head * 64 + d + 32];
#pragma unroll
        for (int mi = 0; mi < 8; ++mi) {
#pragma unroll
            for (int r = 0; r < 4; ++r) {
                int pos = m0 + wm * 128 + mi * 16 + lg * 4 + r;
                float c = freqs[pos * 64 + d];
                float s = freqs[pos * 64 + 32 + d];
                float t1 = acc[mi][nj][r] + b1;
                float t2 = acc[mi][nj + 2][r] + b2;
                size_t base = (size_t)pos * 4096 + head * 64 + d;
                Qb[base] = f2b(t1 * c - t2 * s);
                Qb[base + 32] = f2b(t2 * c + t1 * s);
            }
        }
    }
}

// ---------------------------------------------------------------- GEMM1b: x @ [k|v]w (N=1024), 128² core
__global__ __launch_bounds__(256) void k_gemm_kv(
        const u16* __restrict__ A, const u16* __restrict__ B,
        const float* __restrict__ kbias, const float* __restrict__ vbias,
        const float* __restrict__ freqs,
        u16* __restrict__ Kb, u16* __restrict__ Vt) {
    __shared__ __align__(16) u16 lsA[128 * 64];
    __shared__ __align__(16) u16 lsB[128 * 64];
    const int bid = blockIdx.x;
    const int swz = (bid & 7) * 32 + (bid >> 3);      // bijective: 256 % 8 == 0
    const int bm = swz & 31, bn = swz >> 5;           // bn 0..7
    const int m0 = bm * 128, n0 = bn * 128;
    const int wid = threadIdx.x >> 6, lane = threadIdx.x & 63;
    const int l15 = lane & 15, lg = lane >> 4;
    const int wr = wid >> 1, wc = wid & 1;
    f32x4 acc[4][4] = {};
    gemm_core128(A, B, m0, n0, 2880, lsA, lsB, acc, wid, lane);

    if (bn < 4) {   // K: bias + RoPE
        const int head = bn * 2 + wc;
#pragma unroll
        for (int ni = 0; ni < 2; ++ni) {
            int d = ni * 16 + l15;                 // 0..31
            float b1 = kbias[head * 64 + d];
            float b2 = kbias[head * 64 + d + 32];
#pragma unroll
            for (int mi = 0; mi < 4; ++mi) {
#pragma unroll
                for (int r = 0; r < 4; ++r) {
                    int pos = m0 + wr * 64 + mi * 16 + lg * 4 + r;
                    float c = freqs[pos * 64 + d];
                    float s = freqs[pos * 64 + 32 + d];
                    float t1 = acc[mi][ni][r] + b1;
                    float t2 = acc[mi][ni + 2][r] + b2;
                    size_t base = (size_t)pos * 512 + head * 64 + d;
                    Kb[base] = f2b(t1 * c - t2 * s);
                    Kb[base + 32] = f2b(t2 * c + t1 * s);
                }
            }
        }
    } else {        // V: bias only, write transposed
        const int kvh = (bn - 4) * 2 + wc;
#pragma unroll
        for (int ni = 0; ni < 4; ++ni) {
            int d = ni * 16 + l15;                 // 0..63
            float b = vbias[kvh * 64 + d];
#pragma unroll
            for (int mi = 0; mi < 4; ++mi)
#pragma unroll
                for (int r = 0; r < 4; ++r) {
                    int pos = m0 + wr * 64 + mi * 16 + lg * 4 + r;
                    Vt[(size_t)(kvh * 64 + d) * 4096 + pos] = f2b(acc[mi][ni][r] + b);
                }
        }
    }
}

// ---------------------------------------------------------------- attention v4: GQA-fused + band-restricted
// Wave wid's q-rows have valid keys only in tiles kt in [wid, wid+8]. Computing
// kt in [wid&~1, min(wid+8,15)|1] = EXACTLY 10 tiles (all wid) covers all valid keys;
// PV chunks kc in [wid>>1, kthi>>1] = exactly 5, spanning exactly the written kt tiles.
// Excluded tiles are fully masked (p==0) -> exact. s[10] statically indexed (rule 20).
__global__ __launch_bounds__(512, 2) void k_attn(const u16* __restrict__ Qb,
                                                 const u16* __restrict__ Kb,
                                                 const u16* __restrict__ Vt,
                                                 const float* __restrict__ sinks,
                                                 u16* __restrict__ attn) {
    const float SCALE = 0.125f;
    __shared__ __align__(16) u16 Ks[256 * 64];       // 32 KB, row = key, swizzled cols
    __shared__ __align__(16) u16 Vs[64 * 256];       // 32 KB, row = d, swizzled pos-chunks
    __shared__ __align__(16) u16 P[8][16][268];      // per-wave P
    const int nblk = blockIdx.x, kh = blockIdx.y;
    const int wid = threadIdx.x >> 6, lane = threadIdx.x & 63;
    const int l15 = lane & 15, lg = lane >> 4;
    const int sw = (l15 & 7) * 8;
    const int win0 = nblk * 128 - 128;
    const int qrow0 = nblk * 128 + wid * 16;
    const int ktlo = wid & ~1;                       // band: 10 kt tiles, 5 kc chunks
    const int kclo = wid >> 1;

    // ---- stage K window: 32 segs of 8 keys x 64 d; 4 GLOAD16/thread
    {
        const int r8 = lane >> 3;
        const int scolK = ((lane & 7) * 8) ^ (r8 * 8);
#pragma unroll
        for (int i = 0; i < 4; ++i) {
            int seg = i * 8 + wid;
            int key = win0 + seg * 8 + r8;
            if (key < 0) key = 0;                              // masked later (p == 0)
            GLOAD16(Kb + (size_t)key * 512 + kh * 64 + scolK, Ks + seg * 512);
        }
    }
    // ---- stage V window: 32 segs of 2 d-rows x 256 pos (swizzle pair as r14)
    {
        const int r2 = lane >> 5;                              // row within seg (0..1)
        const int c32 = lane & 31;                             // physical 16B chunk
#pragma unroll
        for (int i = 0; i < 4; ++i) {
            int seg = i * 8 + wid;
            int row = seg * 2 + r2;                            // d 0..63
            int pos = win0 + ((c32 ^ (row & 7)) * 8);
            if (pos < 0) pos = 0;                              // masked later (p == 0)
            GLOAD16(Vt + (size_t)(kh * 64 + row) * 4096 + pos, Vs + seg * 512);
        }
    }
    __syncthreads();   // drains vmcnt, then barrier

    const int rq = wid * 16 + l15;                             // q row within 128
    bf16x8 qfA[2], qfB[2];
#pragma unroll
    for (int ks = 0; ks < 2; ++ks)                             // prologue: head g=0
        qfA[ks] = ld8(Qb + (size_t)(qrow0 + l15) * 4096 + (kh * 8) * 64 + ks * 32 + lg * 8);

#pragma unroll
    for (int g = 0; g < 8; ++g) {
        const int h = kh * 8 + g;
        const float sinkv = sinks[h];
        const bf16x8* qf = (g & 1) ? qfB : qfA;
        bf16x8* qn = (g & 1) ? qfA : qfB;

        // QK^T swapped over the 10 band tiles: s[t] = score(q=l15, key=(ktlo+t)*16+lg*4+r)
        f32x4 s[10];
#pragma unroll
        for (int t = 0; t < 10; ++t) {
            int kt = ktlo + t;
            f32x4 a = {};
#pragma unroll
            for (int ks = 0; ks < 2; ++ks) {
                bf16x8 kf = ld8(Ks + (kt * 16 + l15) * 64 + ((ks * 32 + lg * 8) ^ sw));
                a = mfma16(kf, qf[ks], a);
            }
            s[t] = a;
        }
        // prefetch next head's Q during softmax
        if (g < 7) {
#pragma unroll
            for (int ks = 0; ks < 2; ++ks)
                qn[ks] = ld8(Qb + (size_t)(qrow0 + l15) * 4096 + (h + 1) * 64 + ks * 32 + lg * 8);
        }
        // mask + scale + lane-local max
        float m = -3e38f;
#pragma unroll
        for (int t = 0; t < 10; ++t) {
            int kt = ktlo + t;
#pragma unroll
            for (int r = 0; r < 4; ++r) {
                int cc = kt * 16 + lg * 4 + r;
                bool valid = (cc > rq) && (cc <= rq + 128) && (win0 + cc >= 0);
                float v = valid ? s[t][r] * SCALE : -1e30f;
                s[t][r] = v;
                m = fmaxf(m, v);
            }
        }
        m = fmaxf(m, __shfl_xor(m, 16, 64));
        m = fmaxf(m, __shfl_xor(m, 32, 64));
        m = fmaxf(m, sinkv);
        float sum = 0.f;
#pragma unroll
        for (int t = 0; t < 10; ++t)
#pragma unroll
            for (int r = 0; r < 4; ++r) {
                float p = __expf(s[t][r] - m);
                s[t][r] = p;
                sum += p;
            }
        sum += __shfl_xor(sum, 16, 64);
        sum += __shfl_xor(sum, 32, 64);
        const float inv = 1.0f / (sum + __expf(sinkv - m));
        // normalized P -> per-wave LDS (u32-packed), band columns only
#pragma unroll
        for (int t = 0; t < 10; ++t) {
            int kt = ktlo + t;
            u32 w0 = (u32)f2b(s[t][0] * inv) | ((u32)f2b(s[t][1] * inv) << 16);
            u32 w1 = (u32)f2b(s[t][2] * inv) | ((u32)f2b(s[t][3] * inv) << 16);
            u32* dst = (u32*)&P[wid][l15][kt * 16 + lg * 4];
            dst[0] = w0;
            dst[1] = w1;
        }

        // PV over the 5 band chunks (span == written kt tiles exactly)
        f32x4 o[4] = {};
#pragma unroll
        for (int u = 0; u < 5; ++u) {
            int kc = kclo + u;
            bf16x8 pa = ld8(&P[wid][l15][kc * 32 + lg * 8]);
#pragma unroll
            for (int dc = 0; dc < 4; ++dc) {
                int row = dc * 16 + l15;
                bf16x8 vf = ld8(Vs + row * 256 + (((kc * 4 + lg) ^ (row & 7)) * 8));
                o[dc] = mfma16(pa, vf, o[dc]);
            }
        }
#pragma unroll
        for (int dc = 0; dc < 4; ++dc)
#pragma unroll
            for (int r = 0; r < 4; ++r) {
                int pos = qrow0 + lg * 4 + r;
                attn[(size_t)pos * 4096 + h * 64 + dc * 16 + l15] = f2b(o[dc][r]);
            }
    }
}

// ---------------------------------------------------------------- GEMM2: attn @ o_w + o_b -> FP32 out
__global__ __launch_bounds__(512, 2) void k_gemm_out(const u16* __restrict__ A,
                                                     const u16* __restrict__ B,
                                                     const float* __restrict__ obias,
                                                     float* __restrict__ out) {
    __shared__ __align__(16) u16 lsA[32768];   // 4 chunks x 2 buf
    __shared__ __align__(16) u16 lsB[24576];   // 3 chunks x 2 buf
    const int bid = blockIdx.x;
    const int swz = (bid & 7) * 30 + (bid >> 3);      // bijective: 240 % 8 == 0
    const int bm = swz & 15, bn = swz >> 4;           // bn 0..14
    const int m0 = bm * 256, n0 = bn * 192;
    const int wid = threadIdx.x >> 6, lane = threadIdx.x & 63;
    const int wm = wid >> 2, wn = wid & 3;
    const int l15 = lane & 15, lg = lane >> 4;
    f32x4 acc[8][3] = {};
    gemm192_core(A, B, m0, n0, 4096, lsA, lsB, acc, wid, lane);
#pragma unroll
    for (int nj = 0; nj < 3; ++nj) {
        int n = n0 + wn * 48 + nj * 16 + l15;         // < 2880 always
        float b = obias[n];
#pragma unroll
        for (int mi = 0; mi < 8; ++mi)
#pragma unroll
            for (int r = 0; r < 4; ++r) {
                int pos = m0 + wm * 128 + mi * 16 + lg * 4 + r;
                out[(size_t)pos * 2880 + n] = acc[mi][nj][r] + b;
            }
    }
}

// ---------------------------------------------------------------- launch
extern "C" void kernel_launch(void* const* d_in, const int* in_sizes, int n_in,
                              void* d_out, int out_size, void* d_ws, size_t ws_size,
                              hipStream_t stream) {
    float* outf = (float*)d_out;
    const int NOUT = 11796480;

    // environment checks -> distinctive error fills (decode via absmax)
    if (ws_size < (size_t)128581632) {
        k_fill<<<(NOUT + 255) / 256, 256, 0, stream>>>(outf, 1111.0f, NOUT);
        return;
    }
    bool sizes_ok = (n_in == 11) && (out_size == NOUT) &&
        in_sizes[0] == 11796480 && in_sizes[1] == 262144 &&
        in_sizes[2] == 11796480 && in_sizes[3] == 4096 &&
        in_sizes[4] == 1474560 && in_sizes[5] == 512 &&
        in_sizes[6] == 1474560 && in_sizes[7] == 512 &&
        in_sizes[8] == 11796480 && in_sizes[9] == 2880 && in_sizes[10] == 64;
    if (!sizes_ok) {
        k_fill<<<(NOUT + 255) / 256, 256, 0, stream>>>(outf, 2222.0f, NOUT);
        return;
    }

    const float* x  = (const float*)d_in[0];
    const float* fr = (const float*)d_in[1];
    const float* qw = (const float*)d_in[2];
    const float* qb = (const float*)d_in[3];
    const float* kw = (const float*)d_in[4];
    const float* kb = (const float*)d_in[5];
    const float* vw = (const float*)d_in[6];
    const float* vb = (const float*)d_in[7];
    const float* ow = (const float*)d_in[8];
    const float* ob = (const float*)d_in[9];
    const float* sk = (const float*)d_in[10];
    char* ws = (char*)d_ws;

    // workspace layout (bytes) — unchanged (known-good ws_size)
    u16* xb   = (u16*)(ws);                       // 4096*2880*2 = 23,592,960
    u16* WT   = (u16*)(ws + 23592960);            // 5120*2880*2 = 29,491,200 (WTo reuses this)
    u16* WTo  = WT;                               // 2880*4096*2 read-reach (fits)
    u16* Qb   = (u16*)(ws + 53084160);            // 4096*4096*2
    u16* Kb   = (u16*)(ws + 86638592);            // 4096*512*2
    u16* Vt   = (u16*)(ws + 90832896);            // 512*4096*2
    u16* attn = (u16*)(ws + 95027200);            // 4096*4096*2 ; total 128,581,632

    k_cvt_x<<<11520, 256, 0, stream>>>(x, xb, 2949120);
    // W^T for QKV: WT[n][k] = w[k][n]; n: 0..4095 Q, 4096..4607 K, 4608..5119 V
    k_transp<<<dim3(64, 45), 256, 0, stream>>>(qw, 2880, 4096, WT, 0, 2880);
    k_transp<<<dim3(8, 45), 256, 0, stream>>>(kw, 2880, 512, WT, 4096, 2880);
    k_transp<<<dim3(8, 45), 256, 0, stream>>>(vw, 2880, 512, WT, 4608, 2880);
    k_gemm_q<<<dim3(256), 512, 0, stream>>>(xb, WT, qb, fr, Qb);
    k_gemm_kv<<<dim3(256), 256, 0, stream>>>(xb, WT + (size_t)4096 * 2880, kb, vb, fr, Kb, Vt);
    k_attn<<<dim3(32, 8), 512, 0, stream>>>(Qb, Kb, Vt, sk, attn);
    // o_w^T (after GEMM1 so it can reuse WT space)
    k_transp<<<dim3(45, 64), 256, 0, stream>>>(ow, 4096, 2880, WTo, 0, 4096);
    k_gemm_out<<<dim3(240), 512, 0, stream>>>(attn, WTo, ob, outf);
}